// Round 2
// baseline (259.798 us; speedup 1.0000x reference)
//
#include <hip/hip_runtime.h>

#define EPS 1e-5f

#define BATCH 16
#define LEN   1024
#define C1    32
#define C2    64
#define NODES 128
#define NF1   100
#define NF2   128
#define NBLOCKS 256

// workspace layout (float offsets)
#define OFF_BAR   0          // 4 ints (grid barrier counters)
#define OFF_STATS 4          // s1[32] q1[32] s2[64] q2[64] = 192
#define OFF_ZZ    196        // 16*100 = 1600
#define OFF_Z     1796       // 16*128*64 = 131072
#define OFF_C1    132868     // 16*32*1024 = 524288
#define OFF_C2    657156     // 16*64*1024 = 1048576
#define ZERO_FLOATS (4 + 192 + 1600 + 131072)

// single-use-per-launch grid barrier; counters zeroed by the in-stream memset.
// agent-scope fence (release) flushes this XCD's dirty L1/L2 to the coherence
// point; acquire after the spin invalidates so post-barrier reads are fresh.
__device__ __forceinline__ void grid_barrier(int* cnt) {
    __syncthreads();
    if (threadIdx.x == 0) {
        __threadfence();
        __hip_atomic_fetch_add(cnt, 1, __ATOMIC_ACQ_REL, __HIP_MEMORY_SCOPE_AGENT);
        while (__hip_atomic_load(cnt, __ATOMIC_ACQUIRE, __HIP_MEMORY_SCOPE_AGENT) < NBLOCKS) {
            __builtin_amdgcn_s_sleep(2);
        }
        __threadfence();
    }
    __syncthreads();
}

__global__ __launch_bounds__(256)
void fused_all(const float* __restrict__ x, const float* __restrict__ bmat,
               const float* __restrict__ c1w, const float* __restrict__ c1b,
               const float* __restrict__ g1, const float* __restrict__ bb1,
               const float* __restrict__ c2w, const float* __restrict__ c2b,
               const float* __restrict__ g2, const float* __restrict__ bb2,
               const float* __restrict__ w1, const float* __restrict__ b1f,
               const float* __restrict__ g3, const float* __restrict__ b3,
               const float* __restrict__ w2, const float* __restrict__ b2f,
               float* __restrict__ out, float* __restrict__ ws) {
    int* bar     = (int*)(ws + OFF_BAR);
    float* stats = ws + OFF_STATS;
    float* zz    = ws + OFF_ZZ;
    float* z     = ws + OFF_Z;
    float* c1    = ws + OFF_C1;
    float* c2    = ws + OFF_C2;

    __shared__ __align__(16) float smem[8832];   // 35.3 KB, max over phases

    const int tid = threadIdx.x;
    const int bid = blockIdx.x;
    const int lane = tid & 63;
    const int wave = tid >> 6;

    // ---------------- Phase 1: conv1 (8->32,K5,pad2) + bias -> c1, BN1 stats
    {
        int ltile = bid & 3, n = (bid >> 2) & 15, zh = bid >> 6;  // 4*16*4
        int l = ltile * 256 + tid;

        float xr[5][8];
#pragma unroll
        for (int dl = 0; dl < 5; ++dl) {
            int lw = l + dl - 2;
            if (lw >= 0 && lw < LEN) {
                const float4* p = (const float4*)(x + ((size_t)n * LEN + lw) * 8);
                float4 a = p[0], b4 = p[1];
                xr[dl][0] = a.x; xr[dl][1] = a.y; xr[dl][2] = a.z; xr[dl][3] = a.w;
                xr[dl][4] = b4.x; xr[dl][5] = b4.y; xr[dl][6] = b4.z; xr[dl][7] = b4.w;
            } else {
#pragma unroll
                for (int ci = 0; ci < 8; ++ci) xr[dl][ci] = 0.f;
            }
        }

        float* red = smem;  // [4 waves][8 ch][2]
#pragma unroll
        for (int cl = 0; cl < 8; ++cl) {
            int c = zh * 8 + cl;
            float acc = c1b[c];
            const float* wc = c1w + c * 40;
#pragma unroll
            for (int ci = 0; ci < 8; ++ci)
#pragma unroll
                for (int dl = 0; dl < 5; ++dl)
                    acc += xr[dl][ci] * wc[ci * 5 + dl];
            c1[((size_t)n * C1 + c) * LEN + l] = acc;

            float s = acc, q = acc * acc;
#pragma unroll
            for (int off = 32; off >= 1; off >>= 1) {
                s += __shfl_xor(s, off);
                q += __shfl_xor(q, off);
            }
            if (lane == 0) { red[(wave * 8 + cl) * 2 + 0] = s; red[(wave * 8 + cl) * 2 + 1] = q; }
        }
        __syncthreads();
        if (tid < 16) {
            int cl = tid >> 1, kind = tid & 1;
            float v = red[(0 * 8 + cl) * 2 + kind] + red[(1 * 8 + cl) * 2 + kind] +
                      red[(2 * 8 + cl) * 2 + kind] + red[(3 * 8 + cl) * 2 + kind];
            atomicAdd(&stats[kind * 32 + zh * 8 + cl], v);
        }
    }
    grid_barrier(&bar[0]);

    // ---------------- Phase 2: BN1+ReLU -> conv2 (32->64,K5) -> c2, BN2 stats
    {
        int ltile = bid & 15, n = bid >> 4;
        int lbase = ltile * 64;
        float* sc1 = smem;           // 32
        float* sh1 = smem + 32;      // 32
        float* a1  = smem + 64;      // 32*68 = 2176
        float* red = smem + 2240;    // [4][16][2] = 128

        if (tid < 32) {
            float s = stats[tid], q = stats[32 + tid];
            float mean = s * (1.f / 16384.f);
            float var = q * (1.f / 16384.f) - mean * mean;
            float rs = rsqrtf(var + EPS);
            float sc = g1[tid] * rs;
            sc1[tid] = sc;
            sh1[tid] = bb1[tid] - mean * sc;
        }
        __syncthreads();

        for (int idx = tid; idx < 32 * 68; idx += 256) {
            int ci = idx / 68, lo = idx - ci * 68;
            int lg = lbase + lo - 2;
            float v = 0.f;
            if (lg >= 0 && lg < LEN) v = c1[((size_t)n * C1 + ci) * LEN + lg];
            a1[idx] = fmaxf(0.f, v * sc1[ci] + sh1[ci]);
        }
        __syncthreads();

        int l = tid & 63;
        int wv = __builtin_amdgcn_readfirstlane(tid >> 6);
        int cobase = wv * 16;

        float acc[16];
#pragma unroll
        for (int u = 0; u < 16; ++u) acc[u] = c2b[cobase + u];

        for (int ci = 0; ci < 32; ++ci) {
            float v0 = a1[ci * 68 + l + 0];
            float v1 = a1[ci * 68 + l + 1];
            float v2 = a1[ci * 68 + l + 2];
            float v3 = a1[ci * 68 + l + 3];
            float v4 = a1[ci * 68 + l + 4];
#pragma unroll
            for (int u = 0; u < 16; ++u) {
                const float* wp = c2w + ((size_t)(cobase + u) * 32 + ci) * 5;  // wave-uniform
                acc[u] += v0 * wp[0] + v1 * wp[1] + v2 * wp[2] + v3 * wp[3] + v4 * wp[4];
            }
        }

        int lg = lbase + l;
#pragma unroll
        for (int u = 0; u < 16; ++u)
            c2[((size_t)n * C2 + cobase + u) * LEN + lg] = acc[u];

        for (int u = 0; u < 16; ++u) {
            float s = acc[u], q = acc[u] * acc[u];
#pragma unroll
            for (int off = 32; off >= 1; off >>= 1) {
                s += __shfl_xor(s, off);
                q += __shfl_xor(q, off);
            }
            if (lane == 0) { red[(wave * 16 + u) * 2 + 0] = s; red[(wave * 16 + u) * 2 + 1] = q; }
        }
        __syncthreads();
        if (tid < 128) {
            int w4 = tid >> 5, rem = tid & 31;
            int u = rem >> 1, kind = rem & 1;
            int ch = w4 * 16 + u;
            atomicAdd(&stats[64 + kind * 64 + ch], red[(w4 * 16 + u) * 2 + kind]);
        }
    }
    grid_barrier(&bar[1]);

    // ---------------- Phase 3: BN2+ReLU + max-product pool -> z (atomicMax, all >= 0)
    {
        int jt = bid & 1, is = (bid >> 1) & 7, n = bid >> 4;  // 2*8*16
        int jbase = jt * 64;
        int ibase = is * 128;
        float* sc2 = smem;            // 64
        float* sh2 = smem + 64;       // 64
        float* bt  = smem + 128;      // 64*68
        float* ht  = smem + 4480;     // 64*68

        if (tid < 64) {
            float s = stats[64 + tid], q = stats[128 + tid];
            float mean = s * (1.f / 16384.f);
            float var = q * (1.f / 16384.f) - mean * mean;
            float rs = rsqrtf(var + EPS);
            float sc = g2[tid] * rs;
            sc2[tid] = sc;
            sh2[tid] = bb2[tid] - mean * sc;
        }
        __syncthreads();

        float mx[16];
#pragma unroll
        for (int u = 0; u < 16; ++u) mx[u] = 0.f;

        int jj = (tid >> 4) * 4, kk = (tid & 15) * 4;

        for (int ic = 0; ic < 2; ++ic) {
            int ib = ibase + ic * 64;
            {   // b tile [64 i][64 j], stride 68
                int il = tid >> 2, jq = (tid & 3) * 16;
                const float4* p = (const float4*)(bmat + ((size_t)n * LEN + ib + il) * NODES + jbase + jq);
                float* d = &bt[il * 68 + jq];
#pragma unroll
                for (int r = 0; r < 4; ++r) {
                    float4 a = p[r];
                    d[r * 4 + 0] = a.x; d[r * 4 + 1] = a.y; d[r * 4 + 2] = a.z; d[r * 4 + 3] = a.w;
                }
            }
            {   // h tile [64 i][64 k] transposed, BN2+ReLU applied, stride 68
                int kc = tid >> 2, iq = tid & 3;
                float sc = sc2[kc], sh = sh2[kc];
                const float4* p = (const float4*)(c2 + ((size_t)n * C2 + kc) * LEN + ib + iq * 16);
#pragma unroll
                for (int r = 0; r < 4; ++r) {
                    float4 hv = p[r];
                    int i0 = iq * 16 + r * 4;
                    ht[(i0 + 0) * 68 + kc] = fmaxf(0.f, hv.x * sc + sh);
                    ht[(i0 + 1) * 68 + kc] = fmaxf(0.f, hv.y * sc + sh);
                    ht[(i0 + 2) * 68 + kc] = fmaxf(0.f, hv.z * sc + sh);
                    ht[(i0 + 3) * 68 + kc] = fmaxf(0.f, hv.w * sc + sh);
                }
            }
            __syncthreads();
#pragma unroll 2
            for (int i = 0; i < 64; ++i) {
                float4 bv = *(const float4*)&bt[i * 68 + jj];
                float4 hv = *(const float4*)&ht[i * 68 + kk];
                float bb[4] = {bv.x, bv.y, bv.z, bv.w};
                float hh[4] = {hv.x, hv.y, hv.z, hv.w};
#pragma unroll
                for (int a = 0; a < 4; ++a)
#pragma unroll
                    for (int c = 0; c < 4; ++c)
                        mx[a * 4 + c] = fmaxf(mx[a * 4 + c], bb[a] * hh[c]);
            }
            __syncthreads();
        }
#pragma unroll
        for (int a = 0; a < 4; ++a)
#pragma unroll
            for (int c = 0; c < 4; ++c) {
                int j = jbase + jj + a, k = kk + c;
                atomicMax((unsigned int*)&z[((size_t)n * NODES + j) * 64 + k],
                          __float_as_uint(mx[a * 4 + c]));
            }
    }
    grid_barrier(&bar[2]);

    // ---------------- Phase 4: FC1 partial dots into zz (200 active blocks)
    if (bid < 200) {
        int f = bid >> 1, half = bid & 1;
        int base = half * 4096;
        float* red = smem;  // [4][16]

        float acc[16];
#pragma unroll
        for (int m = 0; m < 16; ++m) acc[m] = 0.f;

        for (int q = 0; q < 16; ++q) {
            int idx = base + q * 256 + tid;
            float wv = w1[(size_t)f * 8192 + idx];
#pragma unroll
            for (int m = 0; m < 16; ++m)
                acc[m] += wv * z[(size_t)m * 8192 + idx];
        }

        for (int m = 0; m < 16; ++m) {
            float s = acc[m];
#pragma unroll
            for (int off = 32; off >= 1; off >>= 1) s += __shfl_xor(s, off);
            if (lane == 0) red[wave * 16 + m] = s;
        }
        __syncthreads();
        if (tid < 16) {
            float v = red[0 * 16 + tid] + red[1 * 16 + tid] + red[2 * 16 + tid] + red[3 * 16 + tid];
            atomicAdd(&zz[tid * NF1 + f], v);
        }
    }
    grid_barrier(&bar[3]);

    // ---------------- Phase 5: +b1, BN3 over batch, ReLU, FC2 -> out (16 active blocks)
    if (bid < 16) {
        int n = bid;
        float* zzl = smem;          // 1600
        float* sc3 = smem + 1600;   // 100
        float* sh3 = smem + 1700;   // 100

        for (int idx = tid; idx < BATCH * NF1; idx += 256) {
            int f = idx % NF1;
            zzl[idx] = zz[idx] + b1f[f];
        }
        __syncthreads();
        if (tid < NF1) {
            float s = 0.f, q = 0.f;
#pragma unroll
            for (int m = 0; m < BATCH; ++m) {
                float v = zzl[m * NF1 + tid];
                s += v; q += v * v;
            }
            float mean = s * (1.f / 16.f);
            float var = q * (1.f / 16.f) - mean * mean;
            float rs = rsqrtf(var + EPS);
            float sc = g3[tid] * rs;
            sc3[tid] = sc;
            sh3[tid] = b3[tid] - mean * sc;
        }
        __syncthreads();
        for (int idx = tid; idx < BATCH * NF1; idx += 256) {
            int f = idx % NF1;
            zzl[idx] = fmaxf(0.f, zzl[idx] * sc3[f] + sh3[f]);
        }
        __syncthreads();

        if (tid < NF2) {
            float acc = b2f[tid];
            const float* wr = w2 + (size_t)tid * NF1;
            const float* zr = &zzl[n * NF1];
#pragma unroll 4
            for (int f = 0; f < NF1; ++f)
                acc += zr[f] * wr[f];
            out[n * NF2 + tid] = acc;
        }
    }
}

extern "C" void kernel_launch(void* const* d_in, const int* in_sizes, int n_in,
                              void* d_out, int out_size, void* d_ws, size_t ws_size,
                              hipStream_t stream) {
    const float* x    = (const float*)d_in[0];
    const float* bmat = (const float*)d_in[1];
    const float* c1w  = (const float*)d_in[2];
    const float* c1b  = (const float*)d_in[3];
    const float* g1   = (const float*)d_in[4];
    const float* bb1  = (const float*)d_in[5];
    const float* c2w  = (const float*)d_in[6];
    const float* c2b  = (const float*)d_in[7];
    const float* g2   = (const float*)d_in[8];
    const float* bb2  = (const float*)d_in[9];
    const float* w1   = (const float*)d_in[10];
    const float* b1   = (const float*)d_in[11];
    const float* g3   = (const float*)d_in[12];
    const float* b3   = (const float*)d_in[13];
    const float* w2   = (const float*)d_in[14];
    const float* b2   = (const float*)d_in[15];
    float* out = (float*)d_out;
    float* ws  = (float*)d_ws;

    hipMemsetAsync(ws, 0, ZERO_FLOATS * sizeof(float), stream);
    fused_all<<<NBLOCKS, 256, 0, stream>>>(x, bmat, c1w, c1b, g1, bb1, c2w, c2b,
                                           g2, bb2, w1, b1, g3, b3, w2, b2, out, ws);
}